// Round 8
// baseline (225.284 us; speedup 1.0000x reference)
//
#include <hip/hip_runtime.h>
#include <math.h>

#define N_NODES 50000
#define M_NB 16
#define K_CAPS 8
#define DD 16
#define D_DIM 128
#define ROUTIT 6

// ---------------------------------------------------------------------------
// Cross-lane helpers
// ---------------------------------------------------------------------------
template <int CTRL>
__device__ __forceinline__ float dpp_add(float x) {
    // compiler path (used in fc_norm epilogue only)
    int t = __builtin_amdgcn_update_dpp(0, __float_as_int(x), CTRL, 0xF, 0xF, true);
    return x + __int_as_float(t);
}

__device__ __forceinline__ float xor8_add(float x) {
    // x + x[lane^8] : row_ror:8 within each 16-lane row == xor8, fused DPP add
    float d;
    asm("s_nop 1\n\t"
        "v_add_f32_dpp %0, %1, %1 row_ror:8 row_mask:0xf bank_mask:0xf"
        : "=v"(d) : "v"(x));
    return d;
}

__device__ __forceinline__ float xor16_add(float x) {
#if __has_builtin(__builtin_amdgcn_permlane16_swap)
    unsigned xi = __float_as_uint(x);
    auto r = __builtin_amdgcn_permlane16_swap(xi, xi, false, false);
    return __uint_as_float(r[0]) + __uint_as_float(r[1]);
#else
    return x + __int_as_float(__builtin_amdgcn_ds_swizzle(__float_as_int(x), 0x401F));
#endif
}

__device__ __forceinline__ float xor32_add(float x) {
#if __has_builtin(__builtin_amdgcn_permlane32_swap)
    unsigned xi = __float_as_uint(x);
    auto r = __builtin_amdgcn_permlane32_swap(xi, xi, false, false);
    return __uint_as_float(r[0]) + __uint_as_float(r[1]);
#else
    return x + __shfl_xor(x, 32);
#endif
}

__device__ __forceinline__ float fast_rcp(float x) {
#if __has_builtin(__builtin_amdgcn_rcpf)
    return __builtin_amdgcn_rcpf(x);
#else
    return 1.0f / x;
#endif
}

__device__ __forceinline__ float fast_rsq(float x) {
#if __has_builtin(__builtin_amdgcn_rsqf)
    return __builtin_amdgcn_rsqf(x);
#else
    return 1.0f / sqrtf(x);
#endif
}

__device__ __forceinline__ float fast_exp2(float x) {
#if __has_builtin(__builtin_amdgcn_exp2f)
    return __builtin_amdgcn_exp2f(x);
#else
    return __expf(x * 0.6931471805599453f);   // exp(x*ln2) == 2^x
#endif
}

// Fused-DPP butterfly stage over u[4] (16 floats). s_nop 1 covers the
// VALU-write -> DPP-read hazard at entry; within the block each register's
// DPP read is 16 instructions after its previous write.
#define BFLY16(CTRLSTR)                                                        \
    asm ("s_nop 1\n\t"                                                         \
         "v_add_f32_dpp %0, %0, %0 "   CTRLSTR "\n\t"                          \
         "v_add_f32_dpp %1, %1, %1 "   CTRLSTR "\n\t"                          \
         "v_add_f32_dpp %2, %2, %2 "   CTRLSTR "\n\t"                          \
         "v_add_f32_dpp %3, %3, %3 "   CTRLSTR "\n\t"                          \
         "v_add_f32_dpp %4, %4, %4 "   CTRLSTR "\n\t"                          \
         "v_add_f32_dpp %5, %5, %5 "   CTRLSTR "\n\t"                          \
         "v_add_f32_dpp %6, %6, %6 "   CTRLSTR "\n\t"                          \
         "v_add_f32_dpp %7, %7, %7 "   CTRLSTR "\n\t"                          \
         "v_add_f32_dpp %8, %8, %8 "   CTRLSTR "\n\t"                          \
         "v_add_f32_dpp %9, %9, %9 "   CTRLSTR "\n\t"                          \
         "v_add_f32_dpp %10, %10, %10 " CTRLSTR "\n\t"                         \
         "v_add_f32_dpp %11, %11, %11 " CTRLSTR "\n\t"                         \
         "v_add_f32_dpp %12, %12, %12 " CTRLSTR "\n\t"                         \
         "v_add_f32_dpp %13, %13, %13 " CTRLSTR "\n\t"                         \
         "v_add_f32_dpp %14, %14, %14 " CTRLSTR "\n\t"                         \
         "v_add_f32_dpp %15, %15, %15 " CTRLSTR                                \
         : "+v"(u[0].x), "+v"(u[0].y), "+v"(u[0].z), "+v"(u[0].w),             \
           "+v"(u[1].x), "+v"(u[1].y), "+v"(u[1].z), "+v"(u[1].w),             \
           "+v"(u[2].x), "+v"(u[2].y), "+v"(u[2].z), "+v"(u[2].w),             \
           "+v"(u[3].x), "+v"(u[3].y), "+v"(u[3].z), "+v"(u[3].w))

// ---------------------------------------------------------------------------
// K1: per-capsule L2 normalize
// ---------------------------------------------------------------------------
__global__ void normalize_kernel(const float* __restrict__ x,
                                 float* __restrict__ xn) {
    int tid = blockIdx.x * blockDim.x + threadIdx.x;
    if (tid >= N_NODES * K_CAPS) return;
    const float4* p = reinterpret_cast<const float4*>(x + (size_t)tid * DD);
    float4 a0 = p[0], a1 = p[1], a2 = p[2], a3 = p[3];
    float s = a0.x*a0.x + a0.y*a0.y + a0.z*a0.z + a0.w*a0.w
            + a1.x*a1.x + a1.y*a1.y + a1.z*a1.z + a1.w*a1.w
            + a2.x*a2.x + a2.y*a2.y + a2.z*a2.z + a2.w*a2.w
            + a3.x*a3.x + a3.y*a3.y + a3.z*a3.z + a3.w*a3.w;
    float inv = 1.0f / fmaxf(sqrtf(s), 1e-12f);
    float4* q = reinterpret_cast<float4*>(xn + (size_t)tid * DD);
    a0.x *= inv; a0.y *= inv; a0.z *= inv; a0.w *= inv;
    a1.x *= inv; a1.y *= inv; a1.z *= inv; a1.w *= inv;
    a2.x *= inv; a2.y *= inv; a2.z *= inv; a2.w *= inv;
    a3.x *= inv; a3.y *= inv; a3.z *= inv; a3.w *= inv;
    q[0] = a0; q[1] = a1; q[2] = a2; q[3] = a3;
}

// ---------------------------------------------------------------------------
// K2/K4: dynamic routing. One wave per node.
// lane = mh + 8*k : mh = neighbor-half [0,8) bits[2:0], k = capsule [0,8) bits[5:3]
// Lane holds z[m=mh][k][16d] and z[m=mh+8][k][16d] (8 float4), u/xs of cap k only.
//  - einsum1 dots: fully in-lane
//  - softmax k-sum: xor8 (DPP row_ror:8) + xor16/xor32 (permlane) -> all VALU
//  - einsum2 m-reduce: xor1/xor2 (quad_perm) + xor7 (row_half_mirror); {1,2,7}
//    spans GF(2)^3 -> complete all-reduce over the 8 mh-lanes, zero DS ops
//  - renorm deferred: s2 = rsq(||u||^2)*log2e folded into next logits; exp2
// launch_bounds (256,2): 256-VGPR budget so z/u/xs stay RESIDENT (r7: the
// (256,4) bound forced 40 VGPRs -> per-iteration z reloads, FETCH 183 MB)
// ---------------------------------------------------------------------------
__global__ __launch_bounds__(256, 2)
void routing_kernel(const float* __restrict__ xn,
                    const int* __restrict__ nb,
                    float* __restrict__ out) {
    const int wave = threadIdx.x >> 6;
    const int lane = threadIdx.x & 63;
    const int node = blockIdx.x * 4 + wave;
    const int mh = lane & 7;        // m = mh and mh+8
    const int k  = lane >> 3;       // capsule

    const int idx0 = nb[node * M_NB + mh];
    const int idx1 = nb[node * M_NB + mh + 8];
    const float* zr0 = xn + (size_t)idx0 * D_DIM + k * DD;
    const float* zr1 = xn + (size_t)idx1 * D_DIM + k * DD;

    float4 z0[4], z1[4];
#pragma unroll
    for (int j = 0; j < 4; ++j) {
        z0[j] = *reinterpret_cast<const float4*>(zr0 + j * 4);
        z1[j] = *reinterpret_cast<const float4*>(zr1 + j * 4);
    }

    const float* xrow = xn + (size_t)node * D_DIM + k * DD;
    float4 u[4], xs[4];
#pragma unroll
    for (int j = 0; j < 4; ++j) {
        float4 v = *reinterpret_cast<const float4*>(xrow + j * 4);
        u[j] = v;
        xs[j].x = v.x * 0.125f; xs[j].y = v.y * 0.125f;   // xn/8: folded into the
        xs[j].z = v.z * 0.125f; xs[j].w = v.w * 0.125f;   // 8 lane-partials
    }

    const float LOG2E = 1.4426950408889634f;
    float s2 = LOG2E;               // deferred scale * log2(e); exp via exp2

#pragma unroll
    for (int it = 0; it < ROUTIT; ++it) {
        // ---- einsum1: l[m] = (z[m] . u_raw) * s2   (dots fully in-lane)
        float l0 = z0[0].x * u[0].x;
        l0 = fmaf(z0[0].y, u[0].y, l0); l0 = fmaf(z0[0].z, u[0].z, l0); l0 = fmaf(z0[0].w, u[0].w, l0);
        l0 = fmaf(z0[1].x, u[1].x, l0); l0 = fmaf(z0[1].y, u[1].y, l0); l0 = fmaf(z0[1].z, u[1].z, l0); l0 = fmaf(z0[1].w, u[1].w, l0);
        l0 = fmaf(z0[2].x, u[2].x, l0); l0 = fmaf(z0[2].y, u[2].y, l0); l0 = fmaf(z0[2].z, u[2].z, l0); l0 = fmaf(z0[2].w, u[2].w, l0);
        l0 = fmaf(z0[3].x, u[3].x, l0); l0 = fmaf(z0[3].y, u[3].y, l0); l0 = fmaf(z0[3].z, u[3].z, l0); l0 = fmaf(z0[3].w, u[3].w, l0);
        float l1 = z1[0].x * u[0].x;
        l1 = fmaf(z1[0].y, u[0].y, l1); l1 = fmaf(z1[0].z, u[0].z, l1); l1 = fmaf(z1[0].w, u[0].w, l1);
        l1 = fmaf(z1[1].x, u[1].x, l1); l1 = fmaf(z1[1].y, u[1].y, l1); l1 = fmaf(z1[1].z, u[1].z, l1); l1 = fmaf(z1[1].w, u[1].w, l1);
        l1 = fmaf(z1[2].x, u[2].x, l1); l1 = fmaf(z1[2].y, u[2].y, l1); l1 = fmaf(z1[2].z, u[2].z, l1); l1 = fmaf(z1[2].w, u[2].w, l1);
        l1 = fmaf(z1[3].x, u[3].x, l1); l1 = fmaf(z1[3].y, u[3].y, l1); l1 = fmaf(z1[3].z, u[3].z, l1); l1 = fmaf(z1[3].w, u[3].w, l1);

        // ---- softmax over k (lane bits 3,4,5): all-VALU reduction
        //      |dot*s| bounded -> no max subtraction; e = 2^(l*s2) = e^(l*s)
        float e0 = fast_exp2(l0 * s2);
        float e1 = fast_exp2(l1 * s2);
        float t0 = xor8_add(e0);  t0 = xor16_add(t0); t0 = xor32_add(t0);
        float t1 = xor8_add(e1);  t1 = xor16_add(t1); t1 = xor32_add(t1);
        float p0 = e0 * fast_rcp(t0);
        float p1 = e1 * fast_rcp(t1);

        // ---- einsum2 lane-partial: z0*p0 + z1*p1 + xn/8
#pragma unroll
        for (int j = 0; j < 4; ++j) {
            u[j].x = fmaf(z1[j].x, p1, fmaf(z0[j].x, p0, xs[j].x));
            u[j].y = fmaf(z1[j].y, p1, fmaf(z0[j].y, p0, xs[j].y));
            u[j].z = fmaf(z1[j].z, p1, fmaf(z0[j].z, p0, xs[j].z));
            u[j].w = fmaf(z1[j].w, p1, fmaf(z0[j].w, p0, xs[j].w));
        }
        // ---- m-reduce over mh bits[2:0]: pure fused-DPP butterfly
        // {1,2,7} is a GF(2)^3 basis -> full all-reduce over 8 contiguous lanes
        BFLY16("quad_perm:[1,0,3,2] row_mask:0xf bank_mask:0xf");  // xor 1
        BFLY16("quad_perm:[2,3,0,1] row_mask:0xf bank_mask:0xf");  // xor 2
        BFLY16("row_half_mirror row_mask:0xf bank_mask:0xf");      // xor 7

        // ---- deferred renorm: scale only (all but last iteration), in-lane
        if (it < ROUTIT - 1) {
            float ta = u[0].x * u[0].x;
            ta = fmaf(u[0].y, u[0].y, ta); ta = fmaf(u[0].z, u[0].z, ta); ta = fmaf(u[0].w, u[0].w, ta);
            ta = fmaf(u[1].x, u[1].x, ta); ta = fmaf(u[1].y, u[1].y, ta); ta = fmaf(u[1].z, u[1].z, ta); ta = fmaf(u[1].w, u[1].w, ta);
            float tb = u[2].x * u[2].x;
            tb = fmaf(u[2].y, u[2].y, tb); tb = fmaf(u[2].z, u[2].z, tb); tb = fmaf(u[2].w, u[2].w, tb);
            tb = fmaf(u[3].x, u[3].x, tb); tb = fmaf(u[3].y, u[3].y, tb); tb = fmaf(u[3].z, u[3].z, tb); tb = fmaf(u[3].w, u[3].w, tb);
            s2 = fast_rsq(fmaxf(ta + tb, 1e-24f)) * LOG2E;
        }
    }

    // ---- output: relu(u_raw). u[0..3] identical across the 8 mh-lanes of each
    // k group; lane mh==j (j<4) stores quad j of cap k. 32 lanes x 16B = 512B.
#pragma unroll
    for (int j = 0; j < 4; ++j) {
        u[j].x = fmaxf(u[j].x, 0.f); u[j].y = fmaxf(u[j].y, 0.f);
        u[j].z = fmaxf(u[j].z, 0.f); u[j].w = fmaxf(u[j].w, 0.f);
    }
#pragma unroll
    for (int j = 0; j < 4; ++j) {
        if (mh == j) {
            *reinterpret_cast<float4*>(out + (size_t)node * D_DIM + k * DD + j * 4) = u[j];
        }
    }
}

// ---------------------------------------------------------------------------
// K3: xn1 = normalize_per_capsule( relu( h0 @ W^T + b ) )  (unchanged, ~16us)
// Wt4[k4*129 + col]: conflict-free by construction (consecutive float4 reads)
// ---------------------------------------------------------------------------
__global__ __launch_bounds__(256, 2)
void fc_norm_kernel(const float* __restrict__ h,
                    const float* __restrict__ W,
                    const float* __restrict__ b,
                    float* __restrict__ xnout) {
    __shared__ float4 Wt4[32 * 129];     // 66048 B
    __shared__ float4 hrow4[8 * 32];     // 4096 B

    const float4* W4 = reinterpret_cast<const float4*>(W);
    for (int t = threadIdx.x; t < 128 * 32; t += 256) {
        Wt4[(t & 31) * 129 + (t >> 5)] = W4[t];
    }
    __syncthreads();

    const int col = threadIdx.x & 127;
    const int rr  = threadIdx.x >> 7;          // 0 -> rows 0..3, 1 -> rows 4..7
    const float bias = b[col];

    for (int row0 = blockIdx.x * 8; row0 < N_NODES; row0 += gridDim.x * 8) {
        __syncthreads();
        {
            int t = threadIdx.x;
            hrow4[t] = *reinterpret_cast<const float4*>(
                h + (size_t)(row0 + (t >> 5)) * D_DIM + (t & 31) * 4);
        }
        __syncthreads();

        float acc0 = bias, acc1 = bias, acc2 = bias, acc3 = bias;
#pragma unroll
        for (int k4 = 0; k4 < 32; ++k4) {
            float4 w4 = Wt4[k4 * 129 + col];
            float4 h0 = hrow4[(rr * 4 + 0) * 32 + k4];
            float4 h1 = hrow4[(rr * 4 + 1) * 32 + k4];
            float4 h2 = hrow4[(rr * 4 + 2) * 32 + k4];
            float4 h3 = hrow4[(rr * 4 + 3) * 32 + k4];
            acc0 = fmaf(w4.x, h0.x, acc0); acc0 = fmaf(w4.y, h0.y, acc0);
            acc0 = fmaf(w4.z, h0.z, acc0); acc0 = fmaf(w4.w, h0.w, acc0);
            acc1 = fmaf(w4.x, h1.x, acc1); acc1 = fmaf(w4.y, h1.y, acc1);
            acc1 = fmaf(w4.z, h1.z, acc1); acc1 = fmaf(w4.w, h1.w, acc1);
            acc2 = fmaf(w4.x, h2.x, acc2); acc2 = fmaf(w4.y, h2.y, acc2);
            acc2 = fmaf(w4.z, h2.z, acc2); acc2 = fmaf(w4.w, h2.w, acc2);
            acc3 = fmaf(w4.x, h3.x, acc3); acc3 = fmaf(w4.y, h3.y, acc3);
            acc3 = fmaf(w4.z, h3.z, acc3); acc3 = fmaf(w4.w, h3.w, acc3);
        }

        float a[4] = {fmaxf(acc0, 0.f), fmaxf(acc1, 0.f),
                      fmaxf(acc2, 0.f), fmaxf(acc3, 0.f)};
#pragma unroll
        for (int j = 0; j < 4; ++j) {
            float s = a[j] * a[j];
            s = dpp_add<0xB1>(s);
            s = dpp_add<0x4E>(s);
            s = dpp_add<0x141>(s);
            s = dpp_add<0x140>(s);
            float inv = fast_rsq(fmaxf(s, 1e-24f));
            xnout[(size_t)(row0 + rr * 4 + j) * D_DIM + col] = a[j] * inv;
        }
    }
}

// ---------------------------------------------------------------------------
extern "C" void kernel_launch(void* const* d_in, const int* in_sizes, int n_in,
                              void* d_out, int out_size, void* d_ws, size_t ws_size,
                              hipStream_t stream) {
    const float* x  = (const float*)d_in[0];
    const int*   nb = (const int*)d_in[1];
    const float* W  = (const float*)d_in[2];
    const float* bb = (const float*)d_in[3];
    float* out = (float*)d_out;

    float* xnbuf = (float*)d_ws;                          // 25.6 MB
    float* h0    = xnbuf + (size_t)N_NODES * D_DIM;       // 25.6 MB

    // layer 0
    normalize_kernel<<<(N_NODES * K_CAPS + 255) / 256, 256, 0, stream>>>(x, xnbuf);
    routing_kernel<<<N_NODES / 4, 256, 0, stream>>>(xnbuf, nb, h0);
    // layer 1  (50000 % 8 == 0 -> no row tail)
    fc_norm_kernel<<<1024, 256, 0, stream>>>(h0, W, bb, xnbuf);
    routing_kernel<<<N_NODES / 4, 256, 0, stream>>>(xnbuf, nb, out);
}

// Round 9
// 224.167 us; speedup vs baseline: 1.0050x; 1.0050x over previous
//
#include <hip/hip_runtime.h>
#include <math.h>

#define N_NODES 50000
#define M_NB 16
#define K_CAPS 8
#define DD 16
#define D_DIM 128
#define ROUTIT 6

// ---------------------------------------------------------------------------
// Cross-lane helpers
// ---------------------------------------------------------------------------
template <int CTRL>
__device__ __forceinline__ float dpp_add(float x) {
    // compiler path (used in fc_norm epilogue only)
    int t = __builtin_amdgcn_update_dpp(0, __float_as_int(x), CTRL, 0xF, 0xF, true);
    return x + __int_as_float(t);
}

__device__ __forceinline__ float xor8_add(float x) {
    // x + x[lane^8] : row_ror:8 within each 16-lane row == xor8, fused DPP add
    float d;
    asm("s_nop 1\n\t"
        "v_add_f32_dpp %0, %1, %1 row_ror:8 row_mask:0xf bank_mask:0xf"
        : "=v"(d) : "v"(x));
    return d;
}

__device__ __forceinline__ float xor16_add(float x) {
#if __has_builtin(__builtin_amdgcn_permlane16_swap)
    unsigned xi = __float_as_uint(x);
    auto r = __builtin_amdgcn_permlane16_swap(xi, xi, false, false);
    return __uint_as_float(r[0]) + __uint_as_float(r[1]);
#else
    return x + __int_as_float(__builtin_amdgcn_ds_swizzle(__float_as_int(x), 0x401F));
#endif
}

__device__ __forceinline__ float xor32_add(float x) {
#if __has_builtin(__builtin_amdgcn_permlane32_swap)
    unsigned xi = __float_as_uint(x);
    auto r = __builtin_amdgcn_permlane32_swap(xi, xi, false, false);
    return __uint_as_float(r[0]) + __uint_as_float(r[1]);
#else
    return x + __shfl_xor(x, 32);
#endif
}

__device__ __forceinline__ float fast_rcp(float x) {
#if __has_builtin(__builtin_amdgcn_rcpf)
    return __builtin_amdgcn_rcpf(x);
#else
    return 1.0f / x;
#endif
}

__device__ __forceinline__ float fast_rsq(float x) {
#if __has_builtin(__builtin_amdgcn_rsqf)
    return __builtin_amdgcn_rsqf(x);
#else
    return 1.0f / sqrtf(x);
#endif
}

__device__ __forceinline__ float fast_exp2(float x) {
#if __has_builtin(__builtin_amdgcn_exp2f)
    return __builtin_amdgcn_exp2f(x);
#else
    return __expf(x * 0.6931471805599453f);   // exp(x*ln2) == 2^x
#endif
}

// Pin a float4's components as opaque live VGPR values: the compiler can no
// longer sink/rematerialize the producing loads into the loop (r8: allocator
// chose a 36-VGPR reload schedule; launch bounds alone did not fix it).
#define PIN4(v) asm volatile("" : "+v"(v.x), "+v"(v.y), "+v"(v.z), "+v"(v.w))

// Fused-DPP butterfly stage over u[4] (16 floats). s_nop 1 covers the
// VALU-write -> DPP-read hazard at entry; within the block each register's
// DPP read is 16 instructions after its previous write.
#define BFLY16(CTRLSTR)                                                        \
    asm ("s_nop 1\n\t"                                                         \
         "v_add_f32_dpp %0, %0, %0 "   CTRLSTR "\n\t"                          \
         "v_add_f32_dpp %1, %1, %1 "   CTRLSTR "\n\t"                          \
         "v_add_f32_dpp %2, %2, %2 "   CTRLSTR "\n\t"                          \
         "v_add_f32_dpp %3, %3, %3 "   CTRLSTR "\n\t"                          \
         "v_add_f32_dpp %4, %4, %4 "   CTRLSTR "\n\t"                          \
         "v_add_f32_dpp %5, %5, %5 "   CTRLSTR "\n\t"                          \
         "v_add_f32_dpp %6, %6, %6 "   CTRLSTR "\n\t"                          \
         "v_add_f32_dpp %7, %7, %7 "   CTRLSTR "\n\t"                          \
         "v_add_f32_dpp %8, %8, %8 "   CTRLSTR "\n\t"                          \
         "v_add_f32_dpp %9, %9, %9 "   CTRLSTR "\n\t"                          \
         "v_add_f32_dpp %10, %10, %10 " CTRLSTR "\n\t"                         \
         "v_add_f32_dpp %11, %11, %11 " CTRLSTR "\n\t"                         \
         "v_add_f32_dpp %12, %12, %12 " CTRLSTR "\n\t"                         \
         "v_add_f32_dpp %13, %13, %13 " CTRLSTR "\n\t"                         \
         "v_add_f32_dpp %14, %14, %14 " CTRLSTR "\n\t"                         \
         "v_add_f32_dpp %15, %15, %15 " CTRLSTR                                \
         : "+v"(u[0].x), "+v"(u[0].y), "+v"(u[0].z), "+v"(u[0].w),             \
           "+v"(u[1].x), "+v"(u[1].y), "+v"(u[1].z), "+v"(u[1].w),             \
           "+v"(u[2].x), "+v"(u[2].y), "+v"(u[2].z), "+v"(u[2].w),             \
           "+v"(u[3].x), "+v"(u[3].y), "+v"(u[3].z), "+v"(u[3].w))

// ---------------------------------------------------------------------------
// K1: per-capsule L2 normalize
// ---------------------------------------------------------------------------
__global__ void normalize_kernel(const float* __restrict__ x,
                                 float* __restrict__ xn) {
    int tid = blockIdx.x * blockDim.x + threadIdx.x;
    if (tid >= N_NODES * K_CAPS) return;
    const float4* p = reinterpret_cast<const float4*>(x + (size_t)tid * DD);
    float4 a0 = p[0], a1 = p[1], a2 = p[2], a3 = p[3];
    float s = a0.x*a0.x + a0.y*a0.y + a0.z*a0.z + a0.w*a0.w
            + a1.x*a1.x + a1.y*a1.y + a1.z*a1.z + a1.w*a1.w
            + a2.x*a2.x + a2.y*a2.y + a2.z*a2.z + a2.w*a2.w
            + a3.x*a3.x + a3.y*a3.y + a3.z*a3.z + a3.w*a3.w;
    float inv = 1.0f / fmaxf(sqrtf(s), 1e-12f);
    float4* q = reinterpret_cast<float4*>(xn + (size_t)tid * DD);
    a0.x *= inv; a0.y *= inv; a0.z *= inv; a0.w *= inv;
    a1.x *= inv; a1.y *= inv; a1.z *= inv; a1.w *= inv;
    a2.x *= inv; a2.y *= inv; a2.z *= inv; a2.w *= inv;
    a3.x *= inv; a3.y *= inv; a3.z *= inv; a3.w *= inv;
    q[0] = a0; q[1] = a1; q[2] = a2; q[3] = a3;
}

// ---------------------------------------------------------------------------
// K2/K4: dynamic routing. One wave per node.
// lane = mh + 8*k : mh = neighbor-half [0,8) bits[2:0], k = capsule [0,8) bits[5:3]
// Lane holds z[m=mh][k][16d] and z[m=mh+8][k][16d] (8 float4), u/xs of cap k only.
//  - einsum1 dots: fully in-lane
//  - softmax k-sum: xor8 (DPP row_ror:8) + xor16/xor32 (permlane) -> all VALU
//  - einsum2 m-reduce: xor1/xor2 (quad_perm) + xor7 (row_half_mirror); {1,2,7}
//    spans GF(2)^3 -> complete all-reduce over the 8 mh-lanes, zero DS ops
//  - renorm deferred: s2 = rsq(||u||^2)*log2e folded into next logits; exp2
// z/xs PINNED as opaque register values (PIN4) so the allocator cannot choose
// the 36-VGPR reload schedule seen in r7/r8.
// ---------------------------------------------------------------------------
__global__ __launch_bounds__(256)
void routing_kernel(const float* __restrict__ xn,
                    const int* __restrict__ nb,
                    float* __restrict__ out) {
    const int wave = threadIdx.x >> 6;
    const int lane = threadIdx.x & 63;
    const int node = blockIdx.x * 4 + wave;
    const int mh = lane & 7;        // m = mh and mh+8
    const int k  = lane >> 3;       // capsule

    const int idx0 = nb[node * M_NB + mh];
    const int idx1 = nb[node * M_NB + mh + 8];
    const float* zr0 = xn + (size_t)idx0 * D_DIM + k * DD;
    const float* zr1 = xn + (size_t)idx1 * D_DIM + k * DD;

    float4 z0[4], z1[4];
#pragma unroll
    for (int j = 0; j < 4; ++j) {
        z0[j] = *reinterpret_cast<const float4*>(zr0 + j * 4);
        z1[j] = *reinterpret_cast<const float4*>(zr1 + j * 4);
    }

    const float* xrow = xn + (size_t)node * D_DIM + k * DD;
    float4 u[4], xs[4];
#pragma unroll
    for (int j = 0; j < 4; ++j) {
        float4 v = *reinterpret_cast<const float4*>(xrow + j * 4);
        u[j] = v;
        xs[j].x = v.x * 0.125f; xs[j].y = v.y * 0.125f;   // xn/8: folded into the
        xs[j].z = v.z * 0.125f; xs[j].w = v.w * 0.125f;   // 8 lane-partials
    }

    // Pin gathered operands in registers for the whole routing loop.
#pragma unroll
    for (int j = 0; j < 4; ++j) { PIN4(z0[j]); PIN4(z1[j]); PIN4(xs[j]); }

    const float LOG2E = 1.4426950408889634f;
    float s2 = LOG2E;               // deferred scale * log2(e); exp via exp2

#pragma unroll
    for (int it = 0; it < ROUTIT; ++it) {
        // ---- einsum1: l[m] = (z[m] . u_raw) * s2   (dots fully in-lane)
        float l0 = z0[0].x * u[0].x;
        l0 = fmaf(z0[0].y, u[0].y, l0); l0 = fmaf(z0[0].z, u[0].z, l0); l0 = fmaf(z0[0].w, u[0].w, l0);
        l0 = fmaf(z0[1].x, u[1].x, l0); l0 = fmaf(z0[1].y, u[1].y, l0); l0 = fmaf(z0[1].z, u[1].z, l0); l0 = fmaf(z0[1].w, u[1].w, l0);
        l0 = fmaf(z0[2].x, u[2].x, l0); l0 = fmaf(z0[2].y, u[2].y, l0); l0 = fmaf(z0[2].z, u[2].z, l0); l0 = fmaf(z0[2].w, u[2].w, l0);
        l0 = fmaf(z0[3].x, u[3].x, l0); l0 = fmaf(z0[3].y, u[3].y, l0); l0 = fmaf(z0[3].z, u[3].z, l0); l0 = fmaf(z0[3].w, u[3].w, l0);
        float l1 = z1[0].x * u[0].x;
        l1 = fmaf(z1[0].y, u[0].y, l1); l1 = fmaf(z1[0].z, u[0].z, l1); l1 = fmaf(z1[0].w, u[0].w, l1);
        l1 = fmaf(z1[1].x, u[1].x, l1); l1 = fmaf(z1[1].y, u[1].y, l1); l1 = fmaf(z1[1].z, u[1].z, l1); l1 = fmaf(z1[1].w, u[1].w, l1);
        l1 = fmaf(z1[2].x, u[2].x, l1); l1 = fmaf(z1[2].y, u[2].y, l1); l1 = fmaf(z1[2].z, u[2].z, l1); l1 = fmaf(z1[2].w, u[2].w, l1);
        l1 = fmaf(z1[3].x, u[3].x, l1); l1 = fmaf(z1[3].y, u[3].y, l1); l1 = fmaf(z1[3].z, u[3].z, l1); l1 = fmaf(z1[3].w, u[3].w, l1);

        // ---- softmax over k (lane bits 3,4,5): all-VALU reduction
        //      |dot*s2| <= log2e -> no max subtraction; e = 2^(l*s2) = e^(l*s)
        float e0 = fast_exp2(l0 * s2);
        float e1 = fast_exp2(l1 * s2);
        float t0 = xor8_add(e0);  t0 = xor16_add(t0); t0 = xor32_add(t0);
        float t1 = xor8_add(e1);  t1 = xor16_add(t1); t1 = xor32_add(t1);
        float p0 = e0 * fast_rcp(t0);
        float p1 = e1 * fast_rcp(t1);

        // ---- einsum2 lane-partial: z0*p0 + z1*p1 + xn/8
#pragma unroll
        for (int j = 0; j < 4; ++j) {
            u[j].x = fmaf(z1[j].x, p1, fmaf(z0[j].x, p0, xs[j].x));
            u[j].y = fmaf(z1[j].y, p1, fmaf(z0[j].y, p0, xs[j].y));
            u[j].z = fmaf(z1[j].z, p1, fmaf(z0[j].z, p0, xs[j].z));
            u[j].w = fmaf(z1[j].w, p1, fmaf(z0[j].w, p0, xs[j].w));
        }
        // ---- m-reduce over mh bits[2:0]: pure fused-DPP butterfly
        // {1,2,7} is a GF(2)^3 basis -> full all-reduce over 8 contiguous lanes
        BFLY16("quad_perm:[1,0,3,2] row_mask:0xf bank_mask:0xf");  // xor 1
        BFLY16("quad_perm:[2,3,0,1] row_mask:0xf bank_mask:0xf");  // xor 2
        BFLY16("row_half_mirror row_mask:0xf bank_mask:0xf");      // xor 7

        // ---- deferred renorm: scale only (all but last iteration), in-lane
        if (it < ROUTIT - 1) {
            float ta = u[0].x * u[0].x;
            ta = fmaf(u[0].y, u[0].y, ta); ta = fmaf(u[0].z, u[0].z, ta); ta = fmaf(u[0].w, u[0].w, ta);
            ta = fmaf(u[1].x, u[1].x, ta); ta = fmaf(u[1].y, u[1].y, ta); ta = fmaf(u[1].z, u[1].z, ta); ta = fmaf(u[1].w, u[1].w, ta);
            float tb = u[2].x * u[2].x;
            tb = fmaf(u[2].y, u[2].y, tb); tb = fmaf(u[2].z, u[2].z, tb); tb = fmaf(u[2].w, u[2].w, tb);
            tb = fmaf(u[3].x, u[3].x, tb); tb = fmaf(u[3].y, u[3].y, tb); tb = fmaf(u[3].z, u[3].z, tb); tb = fmaf(u[3].w, u[3].w, tb);
            s2 = fast_rsq(fmaxf(ta + tb, 1e-24f)) * LOG2E;
        }
    }

    // ---- output: relu(u_raw). u[0..3] identical across the 8 mh-lanes of each
    // k group; lane mh==j (j<4) stores quad j of cap k. 32 lanes x 16B = 512B.
#pragma unroll
    for (int j = 0; j < 4; ++j) {
        u[j].x = fmaxf(u[j].x, 0.f); u[j].y = fmaxf(u[j].y, 0.f);
        u[j].z = fmaxf(u[j].z, 0.f); u[j].w = fmaxf(u[j].w, 0.f);
    }
#pragma unroll
    for (int j = 0; j < 4; ++j) {
        if (mh == j) {
            *reinterpret_cast<float4*>(out + (size_t)node * D_DIM + k * DD + j * 4) = u[j];
        }
    }
}

// ---------------------------------------------------------------------------
// K3: xn1 = normalize_per_capsule( relu( h0 @ W^T + b ) )  (unchanged, ~16us)
// Wt4[k4*129 + col]: conflict-free by construction (consecutive float4 reads)
// ---------------------------------------------------------------------------
__global__ __launch_bounds__(256, 2)
void fc_norm_kernel(const float* __restrict__ h,
                    const float* __restrict__ W,
                    const float* __restrict__ b,
                    float* __restrict__ xnout) {
    __shared__ float4 Wt4[32 * 129];     // 66048 B
    __shared__ float4 hrow4[8 * 32];     // 4096 B

    const float4* W4 = reinterpret_cast<const float4*>(W);
    for (int t = threadIdx.x; t < 128 * 32; t += 256) {
        Wt4[(t & 31) * 129 + (t >> 5)] = W4[t];
    }
    __syncthreads();

    const int col = threadIdx.x & 127;
    const int rr  = threadIdx.x >> 7;          // 0 -> rows 0..3, 1 -> rows 4..7
    const float bias = b[col];

    for (int row0 = blockIdx.x * 8; row0 < N_NODES; row0 += gridDim.x * 8) {
        __syncthreads();
        {
            int t = threadIdx.x;
            hrow4[t] = *reinterpret_cast<const float4*>(
                h + (size_t)(row0 + (t >> 5)) * D_DIM + (t & 31) * 4);
        }
        __syncthreads();

        float acc0 = bias, acc1 = bias, acc2 = bias, acc3 = bias;
#pragma unroll
        for (int k4 = 0; k4 < 32; ++k4) {
            float4 w4 = Wt4[k4 * 129 + col];
            float4 h0 = hrow4[(rr * 4 + 0) * 32 + k4];
            float4 h1 = hrow4[(rr * 4 + 1) * 32 + k4];
            float4 h2 = hrow4[(rr * 4 + 2) * 32 + k4];
            float4 h3 = hrow4[(rr * 4 + 3) * 32 + k4];
            acc0 = fmaf(w4.x, h0.x, acc0); acc0 = fmaf(w4.y, h0.y, acc0);
            acc0 = fmaf(w4.z, h0.z, acc0); acc0 = fmaf(w4.w, h0.w, acc0);
            acc1 = fmaf(w4.x, h1.x, acc1); acc1 = fmaf(w4.y, h1.y, acc1);
            acc1 = fmaf(w4.z, h1.z, acc1); acc1 = fmaf(w4.w, h1.w, acc1);
            acc2 = fmaf(w4.x, h2.x, acc2); acc2 = fmaf(w4.y, h2.y, acc2);
            acc2 = fmaf(w4.z, h2.z, acc2); acc2 = fmaf(w4.w, h2.w, acc2);
            acc3 = fmaf(w4.x, h3.x, acc3); acc3 = fmaf(w4.y, h3.y, acc3);
            acc3 = fmaf(w4.z, h3.z, acc3); acc3 = fmaf(w4.w, h3.w, acc3);
        }

        float a[4] = {fmaxf(acc0, 0.f), fmaxf(acc1, 0.f),
                      fmaxf(acc2, 0.f), fmaxf(acc3, 0.f)};
#pragma unroll
        for (int j = 0; j < 4; ++j) {
            float s = a[j] * a[j];
            s = dpp_add<0xB1>(s);
            s = dpp_add<0x4E>(s);
            s = dpp_add<0x141>(s);
            s = dpp_add<0x140>(s);
            float inv = fast_rsq(fmaxf(s, 1e-24f));
            xnout[(size_t)(row0 + rr * 4 + j) * D_DIM + col] = a[j] * inv;
        }
    }
}

// ---------------------------------------------------------------------------
extern "C" void kernel_launch(void* const* d_in, const int* in_sizes, int n_in,
                              void* d_out, int out_size, void* d_ws, size_t ws_size,
                              hipStream_t stream) {
    const float* x  = (const float*)d_in[0];
    const int*   nb = (const int*)d_in[1];
    const float* W  = (const float*)d_in[2];
    const float* bb = (const float*)d_in[3];
    float* out = (float*)d_out;

    float* xnbuf = (float*)d_ws;                          // 25.6 MB
    float* h0    = xnbuf + (size_t)N_NODES * D_DIM;       // 25.6 MB

    // layer 0
    normalize_kernel<<<(N_NODES * K_CAPS + 255) / 256, 256, 0, stream>>>(x, xnbuf);
    routing_kernel<<<N_NODES / 4, 256, 0, stream>>>(xnbuf, nb, h0);
    // layer 1  (50000 % 8 == 0 -> no row tail)
    fc_norm_kernel<<<1024, 256, 0, stream>>>(h0, W, bb, xnbuf);
    routing_kernel<<<N_NODES / 4, 256, 0, stream>>>(xnbuf, nb, out);
}

// Round 10
// 218.319 us; speedup vs baseline: 1.0319x; 1.0268x over previous
//
#include <hip/hip_runtime.h>
#include <math.h>

#define N_NODES 50000
#define M_NB 16
#define K_CAPS 8
#define DD 16
#define D_DIM 128
#define ROUTIT 6

// ---------------------------------------------------------------------------
// Cross-lane / packed-math helpers
// ---------------------------------------------------------------------------
template <int CTRL>
__device__ __forceinline__ float dpp_add(float x) {
    // compiler path (used in fc_norm epilogue only)
    int t = __builtin_amdgcn_update_dpp(0, __float_as_int(x), CTRL, 0xF, 0xF, true);
    return x + __int_as_float(t);
}

__device__ __forceinline__ float xor8_add(float x) {
    // x + x[lane^8] : row_ror:8 within each 16-lane row == xor8, fused DPP add
    float d;
    asm("s_nop 1\n\t"
        "v_add_f32_dpp %0, %1, %1 row_ror:8 row_mask:0xf bank_mask:0xf"
        : "=v"(d) : "v"(x));
    return d;
}

__device__ __forceinline__ float xor16_add(float x) {
#if __has_builtin(__builtin_amdgcn_permlane16_swap)
    unsigned xi = __float_as_uint(x);
    auto r = __builtin_amdgcn_permlane16_swap(xi, xi, false, false);
    return __uint_as_float(r[0]) + __uint_as_float(r[1]);
#else
    return x + __int_as_float(__builtin_amdgcn_ds_swizzle(__float_as_int(x), 0x401F));
#endif
}

__device__ __forceinline__ float xor32_add(float x) {
#if __has_builtin(__builtin_amdgcn_permlane32_swap)
    unsigned xi = __float_as_uint(x);
    auto r = __builtin_amdgcn_permlane32_swap(xi, xi, false, false);
    return __uint_as_float(r[0]) + __uint_as_float(r[1]);
#else
    return x + __shfl_xor(x, 32);
#endif
}

__device__ __forceinline__ float fast_rcp(float x) {
#if __has_builtin(__builtin_amdgcn_rcpf)
    return __builtin_amdgcn_rcpf(x);
#else
    return 1.0f / x;
#endif
}

__device__ __forceinline__ float fast_rsq(float x) {
#if __has_builtin(__builtin_amdgcn_rsqf)
    return __builtin_amdgcn_rsqf(x);
#else
    return 1.0f / sqrtf(x);
#endif
}

__device__ __forceinline__ float fast_exp2(float x) {
#if __has_builtin(__builtin_amdgcn_exp2f)
    return __builtin_amdgcn_exp2f(x);
#else
    return __expf(x * 0.6931471805599453f);   // exp(x*ln2) == 2^x
#endif
}

// Packed 2xFP32 FMA: d = a*b + c componentwise (VOP3P, CDNA dual-rate fp32)
__device__ __forceinline__ float2 pk_fma(float2 a, float2 b, float2 c) {
    float2 d;
    asm("v_pk_fma_f32 %0, %1, %2, %3" : "=v"(d) : "v"(a), "v"(b), "v"(c));
    return d;
}

// Fused-DPP butterfly stage over u[8] float2 = 16 floats. s_nop 1 covers the
// VALU-write -> DPP-read hazard at entry.
#define BFLY16(CTRLSTR)                                                        \
    asm ("s_nop 1\n\t"                                                         \
         "v_add_f32_dpp %0, %0, %0 "   CTRLSTR "\n\t"                          \
         "v_add_f32_dpp %1, %1, %1 "   CTRLSTR "\n\t"                          \
         "v_add_f32_dpp %2, %2, %2 "   CTRLSTR "\n\t"                          \
         "v_add_f32_dpp %3, %3, %3 "   CTRLSTR "\n\t"                          \
         "v_add_f32_dpp %4, %4, %4 "   CTRLSTR "\n\t"                          \
         "v_add_f32_dpp %5, %5, %5 "   CTRLSTR "\n\t"                          \
         "v_add_f32_dpp %6, %6, %6 "   CTRLSTR "\n\t"                          \
         "v_add_f32_dpp %7, %7, %7 "   CTRLSTR "\n\t"                          \
         "v_add_f32_dpp %8, %8, %8 "   CTRLSTR "\n\t"                          \
         "v_add_f32_dpp %9, %9, %9 "   CTRLSTR "\n\t"                          \
         "v_add_f32_dpp %10, %10, %10 " CTRLSTR "\n\t"                         \
         "v_add_f32_dpp %11, %11, %11 " CTRLSTR "\n\t"                         \
         "v_add_f32_dpp %12, %12, %12 " CTRLSTR "\n\t"                         \
         "v_add_f32_dpp %13, %13, %13 " CTRLSTR "\n\t"                         \
         "v_add_f32_dpp %14, %14, %14 " CTRLSTR "\n\t"                         \
         "v_add_f32_dpp %15, %15, %15 " CTRLSTR                                \
         : "+v"(u[0].x), "+v"(u[0].y), "+v"(u[1].x), "+v"(u[1].y),             \
           "+v"(u[2].x), "+v"(u[2].y), "+v"(u[3].x), "+v"(u[3].y),             \
           "+v"(u[4].x), "+v"(u[4].y), "+v"(u[5].x), "+v"(u[5].y),             \
           "+v"(u[6].x), "+v"(u[6].y), "+v"(u[7].x), "+v"(u[7].y))

// ---------------------------------------------------------------------------
// K1: per-capsule L2 normalize
// ---------------------------------------------------------------------------
__global__ void normalize_kernel(const float* __restrict__ x,
                                 float* __restrict__ xn) {
    int tid = blockIdx.x * blockDim.x + threadIdx.x;
    if (tid >= N_NODES * K_CAPS) return;
    const float4* p = reinterpret_cast<const float4*>(x + (size_t)tid * DD);
    float4 a0 = p[0], a1 = p[1], a2 = p[2], a3 = p[3];
    float s = a0.x*a0.x + a0.y*a0.y + a0.z*a0.z + a0.w*a0.w
            + a1.x*a1.x + a1.y*a1.y + a1.z*a1.z + a1.w*a1.w
            + a2.x*a2.x + a2.y*a2.y + a2.z*a2.z + a2.w*a2.w
            + a3.x*a3.x + a3.y*a3.y + a3.z*a3.z + a3.w*a3.w;
    float inv = 1.0f / fmaxf(sqrtf(s), 1e-12f);
    float4* q = reinterpret_cast<float4*>(xn + (size_t)tid * DD);
    a0.x *= inv; a0.y *= inv; a0.z *= inv; a0.w *= inv;
    a1.x *= inv; a1.y *= inv; a1.z *= inv; a1.w *= inv;
    a2.x *= inv; a2.y *= inv; a2.z *= inv; a2.w *= inv;
    a3.x *= inv; a3.y *= inv; a3.z *= inv; a3.w *= inv;
    q[0] = a0; q[1] = a1; q[2] = a2; q[3] = a3;
}

// ---------------------------------------------------------------------------
// K2/K4: dynamic routing. One wave per node.
// lane = mh + 8*k : mh = neighbor-half [0,8) bits[2:0], k = capsule [0,8) bits[5:3]
// State in float2 pairs; FMA stream via v_pk_fma_f32 (2 FLOP/inst) with 2-way
// accumulator chains (ILP). Butterfly over mh bits {1,2,7} via fused DPP adds
// on the pair halves. Deferred norm scale folded into exp2 logits.
// ---------------------------------------------------------------------------
__global__ __launch_bounds__(256)
void routing_kernel(const float* __restrict__ xn,
                    const int* __restrict__ nb,
                    float* __restrict__ out) {
    const int wave = threadIdx.x >> 6;
    const int lane = threadIdx.x & 63;
    const int node = blockIdx.x * 4 + wave;
    const int mh = lane & 7;        // m = mh and mh+8
    const int k  = lane >> 3;       // capsule

    const int idx0 = nb[node * M_NB + mh];
    const int idx1 = nb[node * M_NB + mh + 8];
    const float* zr0 = xn + (size_t)idx0 * D_DIM + k * DD;
    const float* zr1 = xn + (size_t)idx1 * D_DIM + k * DD;

    float2 z0[8], z1[8];            // d-pairs: z[m][k][2j..2j+1]
#pragma unroll
    for (int j = 0; j < 4; ++j) {
        float4 a = *reinterpret_cast<const float4*>(zr0 + j * 4);
        z0[2*j]     = make_float2(a.x, a.y);
        z0[2*j + 1] = make_float2(a.z, a.w);
        float4 b = *reinterpret_cast<const float4*>(zr1 + j * 4);
        z1[2*j]     = make_float2(b.x, b.y);
        z1[2*j + 1] = make_float2(b.z, b.w);
    }

    const float* xrow = xn + (size_t)node * D_DIM + k * DD;
    float2 u[8], xs[8];
#pragma unroll
    for (int j = 0; j < 4; ++j) {
        float4 v = *reinterpret_cast<const float4*>(xrow + j * 4);
        u[2*j]     = make_float2(v.x, v.y);
        u[2*j + 1] = make_float2(v.z, v.w);
        xs[2*j]     = make_float2(v.x * 0.125f, v.y * 0.125f);  // xn/8 folded
        xs[2*j + 1] = make_float2(v.z * 0.125f, v.w * 0.125f);  // into partials
    }

    const float LOG2E = 1.4426950408889634f;
    const float2 zero2 = make_float2(0.f, 0.f);
    float s2 = LOG2E;               // deferred scale * log2(e); exp via exp2

#pragma unroll
    for (int it = 0; it < ROUTIT; ++it) {
        // ---- einsum1: l[m] = (z[m] . u_raw) * s2 ; 2 pk-chains per dot
        float2 a0 = pk_fma(z0[0], u[0], zero2);
        float2 a1 = pk_fma(z0[1], u[1], zero2);
        a0 = pk_fma(z0[2], u[2], a0);
        a1 = pk_fma(z0[3], u[3], a1);
        a0 = pk_fma(z0[4], u[4], a0);
        a1 = pk_fma(z0[5], u[5], a1);
        a0 = pk_fma(z0[6], u[6], a0);
        a1 = pk_fma(z0[7], u[7], a1);
        float2 b0 = pk_fma(z1[0], u[0], zero2);
        float2 b1 = pk_fma(z1[1], u[1], zero2);
        b0 = pk_fma(z1[2], u[2], b0);
        b1 = pk_fma(z1[3], u[3], b1);
        b0 = pk_fma(z1[4], u[4], b0);
        b1 = pk_fma(z1[5], u[5], b1);
        b0 = pk_fma(z1[6], u[6], b0);
        b1 = pk_fma(z1[7], u[7], b1);
        float l0 = (a0.x + a0.y) + (a1.x + a1.y);
        float l1 = (b0.x + b0.y) + (b1.x + b1.y);

        // ---- softmax over k (lane bits 3,4,5): all-VALU reduction
        //      |dot| <= 1 (unit vectors) -> no max subtraction
        float e0 = fast_exp2(l0 * s2);
        float e1 = fast_exp2(l1 * s2);
        float t0 = xor8_add(e0);  float t1 = xor8_add(e1);
        t0 = xor16_add(t0);       t1 = xor16_add(t1);
        t0 = xor32_add(t0);       t1 = xor32_add(t1);
        float p0 = e0 * fast_rcp(t0);
        float p1 = e1 * fast_rcp(t1);

        // ---- einsum2 lane-partial: z0*p0 + z1*p1 + xn/8 (packed)
        float2 p0b = make_float2(p0, p0);
        float2 p1b = make_float2(p1, p1);
#pragma unroll
        for (int j = 0; j < 8; ++j)
            u[j] = pk_fma(z1[j], p1b, pk_fma(z0[j], p0b, xs[j]));

        // ---- m-reduce over mh bits[2:0]: pure fused-DPP butterfly
        // {1,2,7} is a GF(2)^3 basis -> full all-reduce over 8 contiguous lanes
        BFLY16("quad_perm:[1,0,3,2] row_mask:0xf bank_mask:0xf");  // xor 1
        BFLY16("quad_perm:[2,3,0,1] row_mask:0xf bank_mask:0xf");  // xor 2
        BFLY16("row_half_mirror row_mask:0xf bank_mask:0xf");      // xor 7

        // ---- deferred renorm: scale only (all but last iteration), packed
        if (it < ROUTIT - 1) {
            float2 q0 = pk_fma(u[0], u[0], zero2);
            float2 q1 = pk_fma(u[1], u[1], zero2);
            q0 = pk_fma(u[2], u[2], q0);
            q1 = pk_fma(u[3], u[3], q1);
            q0 = pk_fma(u[4], u[4], q0);
            q1 = pk_fma(u[5], u[5], q1);
            q0 = pk_fma(u[6], u[6], q0);
            q1 = pk_fma(u[7], u[7], q1);
            float nrm = (q0.x + q0.y) + (q1.x + q1.y);
            s2 = fast_rsq(fmaxf(nrm, 1e-24f)) * LOG2E;
        }
    }

    // ---- output: relu(u_raw). u identical across the 8 mh-lanes of each
    // k group; lane mh==j (j<4) stores quad j (pairs 2j,2j+1) of cap k.
#pragma unroll
    for (int j = 0; j < 8; ++j) {
        u[j].x = fmaxf(u[j].x, 0.f);
        u[j].y = fmaxf(u[j].y, 0.f);
    }
#pragma unroll
    for (int j = 0; j < 4; ++j) {
        if (mh == j) {
            float4 v = make_float4(u[2*j].x, u[2*j].y, u[2*j+1].x, u[2*j+1].y);
            *reinterpret_cast<float4*>(out + (size_t)node * D_DIM + k * DD + j * 4) = v;
        }
    }
}

// ---------------------------------------------------------------------------
// K3: xn1 = normalize_per_capsule( relu( h0 @ W^T + b ) )  (unchanged, ~16us)
// Wt4[k4*129 + col]: conflict-free by construction (consecutive float4 reads)
// ---------------------------------------------------------------------------
__global__ __launch_bounds__(256, 2)
void fc_norm_kernel(const float* __restrict__ h,
                    const float* __restrict__ W,
                    const float* __restrict__ b,
                    float* __restrict__ xnout) {
    __shared__ float4 Wt4[32 * 129];     // 66048 B
    __shared__ float4 hrow4[8 * 32];     // 4096 B

    const float4* W4 = reinterpret_cast<const float4*>(W);
    for (int t = threadIdx.x; t < 128 * 32; t += 256) {
        Wt4[(t & 31) * 129 + (t >> 5)] = W4[t];
    }
    __syncthreads();

    const int col = threadIdx.x & 127;
    const int rr  = threadIdx.x >> 7;          // 0 -> rows 0..3, 1 -> rows 4..7
    const float bias = b[col];

    for (int row0 = blockIdx.x * 8; row0 < N_NODES; row0 += gridDim.x * 8) {
        __syncthreads();
        {
            int t = threadIdx.x;
            hrow4[t] = *reinterpret_cast<const float4*>(
                h + (size_t)(row0 + (t >> 5)) * D_DIM + (t & 31) * 4);
        }
        __syncthreads();

        float acc0 = bias, acc1 = bias, acc2 = bias, acc3 = bias;
#pragma unroll
        for (int k4 = 0; k4 < 32; ++k4) {
            float4 w4 = Wt4[k4 * 129 + col];
            float4 h0 = hrow4[(rr * 4 + 0) * 32 + k4];
            float4 h1 = hrow4[(rr * 4 + 1) * 32 + k4];
            float4 h2 = hrow4[(rr * 4 + 2) * 32 + k4];
            float4 h3 = hrow4[(rr * 4 + 3) * 32 + k4];
            acc0 = fmaf(w4.x, h0.x, acc0); acc0 = fmaf(w4.y, h0.y, acc0);
            acc0 = fmaf(w4.z, h0.z, acc0); acc0 = fmaf(w4.w, h0.w, acc0);
            acc1 = fmaf(w4.x, h1.x, acc1); acc1 = fmaf(w4.y, h1.y, acc1);
            acc1 = fmaf(w4.z, h1.z, acc1); acc1 = fmaf(w4.w, h1.w, acc1);
            acc2 = fmaf(w4.x, h2.x, acc2); acc2 = fmaf(w4.y, h2.y, acc2);
            acc2 = fmaf(w4.z, h2.z, acc2); acc2 = fmaf(w4.w, h2.w, acc2);
            acc3 = fmaf(w4.x, h3.x, acc3); acc3 = fmaf(w4.y, h3.y, acc3);
            acc3 = fmaf(w4.z, h3.z, acc3); acc3 = fmaf(w4.w, h3.w, acc3);
        }

        float a[4] = {fmaxf(acc0, 0.f), fmaxf(acc1, 0.f),
                      fmaxf(acc2, 0.f), fmaxf(acc3, 0.f)};
#pragma unroll
        for (int j = 0; j < 4; ++j) {
            float s = a[j] * a[j];
            s = dpp_add<0xB1>(s);
            s = dpp_add<0x4E>(s);
            s = dpp_add<0x141>(s);
            s = dpp_add<0x140>(s);
            float inv = fast_rsq(fmaxf(s, 1e-24f));
            xnout[(size_t)(row0 + rr * 4 + j) * D_DIM + col] = a[j] * inv;
        }
    }
}

// ---------------------------------------------------------------------------
extern "C" void kernel_launch(void* const* d_in, const int* in_sizes, int n_in,
                              void* d_out, int out_size, void* d_ws, size_t ws_size,
                              hipStream_t stream) {
    const float* x  = (const float*)d_in[0];
    const int*   nb = (const int*)d_in[1];
    const float* W  = (const float*)d_in[2];
    const float* bb = (const float*)d_in[3];
    float* out = (float*)d_out;

    float* xnbuf = (float*)d_ws;                          // 25.6 MB
    float* h0    = xnbuf + (size_t)N_NODES * D_DIM;       // 25.6 MB

    // layer 0
    normalize_kernel<<<(N_NODES * K_CAPS + 255) / 256, 256, 0, stream>>>(x, xnbuf);
    routing_kernel<<<N_NODES / 4, 256, 0, stream>>>(xnbuf, nb, h0);
    // layer 1  (50000 % 8 == 0 -> no row tail)
    fc_norm_kernel<<<1024, 256, 0, stream>>>(h0, W, bb, xnbuf);
    routing_kernel<<<N_NODES / 4, 256, 0, stream>>>(xnbuf, nb, out);
}